// Round 2
// baseline (790.484 us; speedup 1.0000x reference)
//
#include <hip/hip_runtime.h>

#define NN 50000
#define EE 800000
#define NDIM 128
#define EDIM 32
#define HH 64

typedef unsigned short u16;
typedef u16 u16x8 __attribute__((ext_vector_type(8)));
typedef __bf16 bf16x8 __attribute__((ext_vector_type(8)));
typedef float f32x4 __attribute__((ext_vector_type(4)));

// ws layout (bytes)
#define OFF_H32  0ull                       // NN*HH f32   = 12,800,000
#define OFF_HBF  12800000ull                // NN*HH u16   =  6,400,000
#define OFF_NWF  19200000ull                // 8192 u16 node_W frags
#define OFF_W1F  (OFF_NWF + 16384ull)       // 4*6144 u16 W1cat frags
#define OFF_W2F  (OFF_W1F + 49152ull)       // 4*4096 u16 W2 frags
#define OFF_FWF  (OFF_W2F + 32768ull)       // 8192 u16 fin_W1 frags
#define OFF_B1P  (OFF_FWF + 16384ull)       // 4*64 f32 fused b1

__device__ __forceinline__ u16 f2bf(float f) {
  unsigned int u = __builtin_bit_cast(unsigned int, f);
  u += 0x7fffu + ((u >> 16) & 1u);
  return (u16)(u >> 16);
}
__device__ __forceinline__ float bf2f(u16 h) {
  unsigned int u = ((unsigned int)h) << 16;
  return __builtin_bit_cast(float, u);
}

// ---------------------------------------------------------------- setup ----
// Packs weights into MFMA B-fragment order and computes the edge-encoder
// fusion  W1e' = edge_W @ W1[64:128,:]  and  b1' = b1 + edge_b @ W1[64:128,:].
// frag(kk,nt,lane,j) = W[kk*32 + (lane>>4)*8 + j][nt*16 + (lane&15)]
__global__ __launch_bounds__(256)
void setup_kernel(const float* __restrict__ node_W, const float* __restrict__ edge_W,
                  const float* __restrict__ edge_b, const float* __restrict__ W1,
                  const float* __restrict__ b1, const float* __restrict__ W2,
                  const float* __restrict__ fin_W1,
                  u16* __restrict__ nWf, u16* __restrict__ W1f, u16* __restrict__ W2f,
                  u16* __restrict__ fWf, float* __restrict__ b1p)
{
  const int tid = threadIdx.x;
  const int blk = blockIdx.x;
  if (blk == 0) {
    for (int idx = tid; idx < 8192; idx += 256) {
      int j = idx & 7, l = (idx >> 3) & 63, nt = (idx >> 9) & 3, kk = idx >> 11;
      int k = kk * 32 + (l >> 4) * 8 + j, n = nt * 16 + (l & 15);
      nWf[idx] = f2bf(node_W[k * HH + n]);
    }
  } else if (blk == 5) {
    for (int idx = tid; idx < 8192; idx += 256) {
      int j = idx & 7, l = (idx >> 3) & 63, nt = (idx >> 9) & 3, kk = idx >> 11;
      int k = kk * 32 + (l >> 4) * 8 + j, n = nt * 16 + (l & 15);
      fWf[idx] = f2bf(fin_W1[k * HH + n]);
    }
  } else {
    const int layer = blk - 1;
    __shared__ float cat[96 * 64];
    const float* W1l = W1 + (size_t)layer * NDIM * HH;
    // rows 0..63 : W1 top half (multiplies h_src+h_dst)
    for (int idx = tid; idx < 4096; idx += 256) cat[idx] = W1l[idx];
    // rows 64..95 : edge_W @ W1 bottom half
    for (int idx = tid; idx < 2048; idx += 256) {
      int a = idx >> 6, n = idx & 63;
      float s = 0.f;
      for (int k = 0; k < 64; ++k) s += edge_W[a * HH + k] * W1l[(64 + k) * HH + n];
      cat[(64 + a) * 64 + n] = s;
    }
    if (tid < 64) {
      float s = b1[layer * HH + tid];
      for (int k = 0; k < 64; ++k) s += edge_b[k] * W1l[(64 + k) * HH + tid];
      b1p[layer * HH + tid] = s;
    }
    __syncthreads();
    for (int idx = tid; idx < 6144; idx += 256) {
      int j = idx & 7, l = (idx >> 3) & 63, nt = (idx >> 9) & 3, kk = idx >> 11;
      int k = kk * 32 + (l >> 4) * 8 + j, n = nt * 16 + (l & 15);
      W1f[layer * 6144 + idx] = f2bf(cat[k * 64 + n]);
    }
    for (int idx = tid; idx < 4096; idx += 256) {
      int j = idx & 7, l = (idx >> 3) & 63, nt = (idx >> 9) & 3, kk = idx >> 11;
      int k = kk * 32 + (l >> 4) * 8 + j, n = nt * 16 + (l & 15);
      W2f[layer * 4096 + idx] = f2bf(W2[((size_t)layer * HH + k) * HH + n]);
    }
  }
}

// ------------------------------------------------------------- node enc ----
#define LDX 136
__global__ __launch_bounds__(256, 2)
void node_enc(const float* __restrict__ x, const u16* __restrict__ nWf,
              const float* __restrict__ node_b, u16* __restrict__ h_bf)
{
  __shared__ u16 Xs[64 * LDX];
  const int tid = threadIdx.x;
  const int base = blockIdx.x * 64;
  const int lane = tid & 63, wv = tid >> 6;
  const int r16 = lane & 15, kg = lane >> 4;

  bf16x8 Bf[4][4];
#pragma unroll
  for (int kk = 0; kk < 4; ++kk)
#pragma unroll
    for (int nt = 0; nt < 4; ++nt)
      Bf[kk][nt] = *reinterpret_cast<const bf16x8*>(nWf + ((kk * 4 + nt) * 64 + lane) * 8);
  float bias[4];
#pragma unroll
  for (int nt = 0; nt < 4; ++nt) bias[nt] = node_b[nt * 16 + r16];

#pragma unroll
  for (int it = 0; it < 4; ++it) {
    int s = it * 256 + tid;
    int r = s >> 4, c = (s & 15) * 8;
    int node = base + r;
    u16x8 o;
    if (node < NN) {
      const f32x4* px = reinterpret_cast<const f32x4*>(x + (size_t)node * NDIM + c);
      f32x4 v0 = px[0], v1 = px[1];
#pragma unroll
      for (int j = 0; j < 4; ++j) { o[j] = f2bf(v0[j]); o[4 + j] = f2bf(v1[j]); }
    } else {
#pragma unroll
      for (int j = 0; j < 8; ++j) o[j] = 0;
    }
    *reinterpret_cast<u16x8*>(&Xs[r * LDX + c]) = o;
  }
  __syncthreads();

  f32x4 acc[4];
#pragma unroll
  for (int nt = 0; nt < 4; ++nt) acc[nt] = (f32x4){0.f, 0.f, 0.f, 0.f};
#pragma unroll
  for (int kk = 0; kk < 4; ++kk) {
    bf16x8 a = *reinterpret_cast<const bf16x8*>(&Xs[(wv * 16 + r16) * LDX + kk * 32 + kg * 8]);
#pragma unroll
    for (int nt = 0; nt < 4; ++nt)
      acc[nt] = __builtin_amdgcn_mfma_f32_16x16x32_bf16(a, Bf[kk][nt], acc[nt], 0, 0, 0);
  }
#pragma unroll
  for (int j = 0; j < 4; ++j) {
    int node = base + wv * 16 + kg * 4 + j;
    if (node < NN) {
#pragma unroll
      for (int nt = 0; nt < 4; ++nt)
        h_bf[(size_t)node * HH + nt * 16 + r16] = f2bf(acc[nt][j] + bias[nt]);
    }
  }
}

// -------------------------------------------------------------- message ----
#define LDI 104   // 96 + 8 pad (u16)
#define LDM 72    // 64 + 8 pad (u16)
__global__ __launch_bounds__(256, 2)
void msg_kernel(const int* __restrict__ ei, const float* __restrict__ edge_attr,
                const u16* __restrict__ h_bf, float* __restrict__ h32,
                const u16* __restrict__ W1f, const u16* __restrict__ W2f,
                const float* __restrict__ b1p, const float* __restrict__ b2a,
                int layer)
{
  __shared__ u16 In[64 * LDI];
  __shared__ u16 M1[4][16 * LDM];
  __shared__ int src_s[64], dst_s[64];

  const int tid = threadIdx.x;
  const int base = blockIdx.x * 64;
  const int lane = tid & 63, wv = tid >> 6;
  const int r16 = lane & 15, kg = lane >> 4;

  if (tid < 64) src_s[tid] = ei[base + tid];
  else if (tid < 128) dst_s[tid - 64] = ei[EE + base + tid - 64];

  bf16x8 B1[3][4], B2[2][4];
  const u16* w1 = W1f + layer * 6144;
  const u16* w2 = W2f + layer * 4096;
#pragma unroll
  for (int kk = 0; kk < 3; ++kk)
#pragma unroll
    for (int nt = 0; nt < 4; ++nt)
      B1[kk][nt] = *reinterpret_cast<const bf16x8*>(w1 + ((kk * 4 + nt) * 64 + lane) * 8);
#pragma unroll
  for (int kk = 0; kk < 2; ++kk)
#pragma unroll
    for (int nt = 0; nt < 4; ++nt)
      B2[kk][nt] = *reinterpret_cast<const bf16x8*>(w2 + ((kk * 4 + nt) * 64 + lane) * 8);
  float b1v[4], b2v[4];
#pragma unroll
  for (int nt = 0; nt < 4; ++nt) {
    b1v[nt] = b1p[layer * HH + nt * 16 + r16];
    b2v[nt] = b2a[layer * HH + nt * 16 + r16];
  }
  __syncthreads();  // indices ready

  // stage s = h_bf[src] + h_bf[dst] into In[:, 0:64]
#pragma unroll
  for (int it = 0; it < 2; ++it) {
    int s = it * 256 + tid;
    int e = s >> 3, c = (s & 7) * 8;
    u16x8 va = *reinterpret_cast<const u16x8*>(h_bf + (size_t)src_s[e] * HH + c);
    u16x8 vb = *reinterpret_cast<const u16x8*>(h_bf + (size_t)dst_s[e] * HH + c);
    u16x8 o;
#pragma unroll
    for (int j = 0; j < 8; ++j) o[j] = f2bf(bf2f(va[j]) + bf2f(vb[j]));
    *reinterpret_cast<u16x8*>(&In[e * LDI + c]) = o;
  }
  // stage edge_attr (f32 -> bf16) into In[:, 64:96]
  {
    int e = tid >> 2, c = (tid & 3) * 8;
    const f32x4* pa = reinterpret_cast<const f32x4*>(edge_attr + (size_t)(base + e) * EDIM + c);
    f32x4 v0 = pa[0], v1 = pa[1];
    u16x8 o;
#pragma unroll
    for (int j = 0; j < 4; ++j) { o[j] = f2bf(v0[j]); o[4 + j] = f2bf(v1[j]); }
    *reinterpret_cast<u16x8*>(&In[e * LDI + 64 + c]) = o;
  }
  __syncthreads();

  // GEMM1: [16,96] @ [96,64]
  f32x4 acc[4];
#pragma unroll
  for (int nt = 0; nt < 4; ++nt) acc[nt] = (f32x4){0.f, 0.f, 0.f, 0.f};
#pragma unroll
  for (int kk = 0; kk < 3; ++kk) {
    bf16x8 a = *reinterpret_cast<const bf16x8*>(&In[(wv * 16 + r16) * LDI + kk * 32 + kg * 8]);
#pragma unroll
    for (int nt = 0; nt < 4; ++nt)
      acc[nt] = __builtin_amdgcn_mfma_f32_16x16x32_bf16(a, B1[kk][nt], acc[nt], 0, 0, 0);
  }
  // relu + bias -> per-wave LDS staging (C layout -> A layout)
#pragma unroll
  for (int nt = 0; nt < 4; ++nt)
#pragma unroll
    for (int j = 0; j < 4; ++j) {
      float v = fmaxf(acc[nt][j] + b1v[nt], 0.f);
      M1[wv][(kg * 4 + j) * LDM + nt * 16 + r16] = f2bf(v);
    }
  __syncthreads();

  // GEMM2: [16,64] @ [64,64]
  f32x4 acc2[4];
#pragma unroll
  for (int nt = 0; nt < 4; ++nt) acc2[nt] = (f32x4){0.f, 0.f, 0.f, 0.f};
#pragma unroll
  for (int kk = 0; kk < 2; ++kk) {
    bf16x8 a = *reinterpret_cast<const bf16x8*>(&M1[wv][r16 * LDM + kk * 32 + kg * 8]);
#pragma unroll
    for (int nt = 0; nt < 4; ++nt)
      acc2[nt] = __builtin_amdgcn_mfma_f32_16x16x32_bf16(a, B2[kk][nt], acc2[nt], 0, 0, 0);
  }
  // scatter-add into h_next (b2 added per edge == segment_sum semantics)
  int dn[4];
#pragma unroll
  for (int j = 0; j < 4; ++j) dn[j] = dst_s[wv * 16 + kg * 4 + j];
#pragma unroll
  for (int j = 0; j < 4; ++j)
#pragma unroll
    for (int nt = 0; nt < 4; ++nt)
      unsafeAtomicAdd(&h32[(size_t)dn[j] * HH + nt * 16 + r16], acc2[nt][j] + b2v[nt]);
}

// ------------------------------------------------------------- h32->bf16 ---
__global__ __launch_bounds__(256)
void cvt_h(const float* __restrict__ h32, u16* __restrict__ h_bf)
{
  size_t i = ((size_t)blockIdx.x * 256 + threadIdx.x) * 8;
  if (i >= (size_t)NN * HH) return;
  const f32x4* p = reinterpret_cast<const f32x4*>(h32 + i);
  f32x4 v0 = p[0], v1 = p[1];
  u16x8 o;
#pragma unroll
  for (int j = 0; j < 4; ++j) { o[j] = f2bf(v0[j]); o[4 + j] = f2bf(v1[j]); }
  *reinterpret_cast<u16x8*>(h_bf + i) = o;
}

// ---------------------------------------------------------------- final ----
#define LDF 136
__global__ __launch_bounds__(256, 2)
void final_kernel(const int* __restrict__ ei, const u16* __restrict__ h_bf,
                  const u16* __restrict__ fWf, const float* __restrict__ fin_b1,
                  const float* __restrict__ fin_W2, const float* __restrict__ fin_b2,
                  float* __restrict__ out)
{
  __shared__ u16 In[64 * LDF];
  __shared__ int src_s[64], dst_s[64];
  const int tid = threadIdx.x;
  const int base = blockIdx.x * 64;
  const int lane = tid & 63, wv = tid >> 6;
  const int r16 = lane & 15, kg = lane >> 4;

  if (tid < 64) src_s[tid] = ei[base + tid];
  else if (tid < 128) dst_s[tid - 64] = ei[EE + base + tid - 64];

  bf16x8 Bf[4][4];
#pragma unroll
  for (int kk = 0; kk < 4; ++kk)
#pragma unroll
    for (int nt = 0; nt < 4; ++nt)
      Bf[kk][nt] = *reinterpret_cast<const bf16x8*>(fWf + ((kk * 4 + nt) * 64 + lane) * 8);
  float b1v[4], w2v[4];
#pragma unroll
  for (int nt = 0; nt < 4; ++nt) {
    b1v[nt] = fin_b1[nt * 16 + r16];
    w2v[nt] = fin_W2[nt * 16 + r16];
  }
  const float bb = fin_b2[0];
  __syncthreads();

  // stage concat(h_src, h_dst) [64 x 128]
#pragma unroll
  for (int it = 0; it < 4; ++it) {
    int s = it * 256 + tid;
    int e = s >> 4, g = s & 15, c = (g & 7) * 8;
    int nd = (g < 8) ? src_s[e] : dst_s[e];
    u16x8 v = *reinterpret_cast<const u16x8*>(h_bf + (size_t)nd * HH + c);
    *reinterpret_cast<u16x8*>(&In[e * LDF + g * 8]) = v;
  }
  __syncthreads();

  f32x4 acc[4];
#pragma unroll
  for (int nt = 0; nt < 4; ++nt) acc[nt] = (f32x4){0.f, 0.f, 0.f, 0.f};
#pragma unroll
  for (int kk = 0; kk < 4; ++kk) {
    bf16x8 a = *reinterpret_cast<const bf16x8*>(&In[(wv * 16 + r16) * LDF + kk * 32 + kg * 8]);
#pragma unroll
    for (int nt = 0; nt < 4; ++nt)
      acc[nt] = __builtin_amdgcn_mfma_f32_16x16x32_bf16(a, Bf[nt == 0 ? kk : kk][nt], acc[nt], 0, 0, 0);
  }
  float p[4];
#pragma unroll
  for (int j = 0; j < 4; ++j) {
    float s = 0.f;
#pragma unroll
    for (int nt = 0; nt < 4; ++nt) s += fmaxf(acc[nt][j] + b1v[nt], 0.f) * w2v[nt];
    p[j] = s;
  }
#pragma unroll
  for (int j = 0; j < 4; ++j)
#pragma unroll
    for (int m = 1; m < 16; m <<= 1)
      p[j] += __shfl_xor(p[j], m, 64);
  if (r16 == 0) {
#pragma unroll
    for (int j = 0; j < 4; ++j)
      out[base + wv * 16 + kg * 4 + j] = p[j] + bb;
  }
}

// ---------------------------------------------------------------- launch ---
extern "C" void kernel_launch(void* const* d_in, const int* in_sizes, int n_in,
                              void* d_out, int out_size, void* d_ws, size_t ws_size,
                              hipStream_t stream)
{
  const float* x      = (const float*)d_in[0];
  const float* eattr  = (const float*)d_in[1];
  const int*   ei     = (const int*)d_in[2];
  const float* node_W = (const float*)d_in[3];
  const float* node_b = (const float*)d_in[4];
  const float* edge_W = (const float*)d_in[5];
  const float* edge_b = (const float*)d_in[6];
  const float* W1     = (const float*)d_in[7];
  const float* b1     = (const float*)d_in[8];
  const float* W2     = (const float*)d_in[9];
  const float* b2     = (const float*)d_in[10];
  const float* fin_W1 = (const float*)d_in[11];
  const float* fin_b1 = (const float*)d_in[12];
  const float* fin_W2 = (const float*)d_in[13];
  const float* fin_b2 = (const float*)d_in[14];

  char* ws   = (char*)d_ws;
  float* h32 = (float*)(ws + OFF_H32);
  u16* h_bf  = (u16*)(ws + OFF_HBF);
  u16* nWf   = (u16*)(ws + OFF_NWF);
  u16* W1f   = (u16*)(ws + OFF_W1F);
  u16* W2f   = (u16*)(ws + OFF_W2F);
  u16* fWf   = (u16*)(ws + OFF_FWF);
  float* b1p = (float*)(ws + OFF_B1P);

  setup_kernel<<<6, 256, 0, stream>>>(node_W, edge_W, edge_b, W1, b1, W2, fin_W1,
                                      nWf, W1f, W2f, fWf, b1p);
  node_enc<<<(NN + 63) / 64, 256, 0, stream>>>(x, nWf, node_b, h_bf);
  for (int l = 0; l < 4; ++l) {
    hipMemsetAsync(h32, 0, (size_t)NN * HH * sizeof(float), stream);
    msg_kernel<<<EE / 64, 256, 0, stream>>>(ei, eattr, h_bf, h32, W1f, W2f, b1p, b2, l);
    cvt_h<<<((size_t)NN * HH / 8 + 255) / 256, 256, 0, stream>>>(h32, h_bf);
  }
  final_kernel<<<EE / 64, 256, 0, stream>>>(ei, h_bf, fWf, fin_b1, fin_W2, fin_b2,
                                            (float*)d_out);
}

// Round 4
// 446.286 us; speedup vs baseline: 1.7713x; 1.7713x over previous
//
#include <hip/hip_runtime.h>

#define NN 50000
#define EE 800000
#define NDIM 128
#define EDIM 32
#define HH 64
#define NBLK 196   // ceil(NN/256)

typedef unsigned short u16;
typedef u16 u16x8 __attribute__((ext_vector_type(8)));
typedef __bf16 bf16x8 __attribute__((ext_vector_type(8)));
typedef float f32x4 __attribute__((ext_vector_type(4)));

// ws layout (bytes)
#define OFF_H32  0ull                        // NN*HH f32 = 12,800,000
#define OFF_HBF  12800000ull                 // NN*HH u16 =  6,400,000
#define OFF_NWF  19200000ull                 // 16,384
#define OFF_W1F  (OFF_NWF + 16384ull)        // 49,152
#define OFF_W2F  (OFF_W1F + 49152ull)        // 32,768
#define OFF_FWF  (OFF_W2F + 32768ull)        // 16,384
#define OFF_B1P  (OFF_FWF + 16384ull)        // 1,024
#define OFF_CUR  (OFF_B1P + 1024ull)         // 50176*4 = 200,704
#define OFF_BSUM (OFF_CUR + 200704ull)       // 1,024
#define OFF_SRCP (OFF_BSUM + 1024ull)        // 3,200,000
#define OFF_DSTP (OFF_SRCP + 3200000ull)     // 3,200,000
#define OFF_EAP  (OFF_DSTP + 3200000ull)     // EE*32*2 = 51,200,000
#define WS_NEED  (OFF_EAP + 51200000ull)

__device__ __forceinline__ u16 f2bf(float f) {
  unsigned int u = __builtin_bit_cast(unsigned int, f);
  u += 0x7fffu + ((u >> 16) & 1u);
  return (u16)(u >> 16);
}
__device__ __forceinline__ float bf2f(u16 h) {
  unsigned int u = ((unsigned int)h) << 16;
  return __builtin_bit_cast(float, u);
}

// ---------------------------------------------------------------- setup ----
// Packs weights into MFMA B-fragment order; fuses edge encoder into W1:
// cat = [W1_top ; edge_W @ W1_bot],  b1' = b1 + edge_b @ W1_bot.
__global__ __launch_bounds__(256)
void setup_kernel(const float* __restrict__ node_W, const float* __restrict__ edge_W,
                  const float* __restrict__ edge_b, const float* __restrict__ W1,
                  const float* __restrict__ b1, const float* __restrict__ W2,
                  const float* __restrict__ fin_W1,
                  u16* __restrict__ nWf, u16* __restrict__ W1f, u16* __restrict__ W2f,
                  u16* __restrict__ fWf, float* __restrict__ b1p)
{
  const int tid = threadIdx.x;
  const int blk = blockIdx.x;
  if (blk == 0) {
    for (int idx = tid; idx < 8192; idx += 256) {
      int j = idx & 7, l = (idx >> 3) & 63, nt = (idx >> 9) & 3, kk = idx >> 11;
      int k = kk * 32 + (l >> 4) * 8 + j, n = nt * 16 + (l & 15);
      nWf[idx] = f2bf(node_W[k * HH + n]);
    }
  } else if (blk == 5) {
    for (int idx = tid; idx < 8192; idx += 256) {
      int j = idx & 7, l = (idx >> 3) & 63, nt = (idx >> 9) & 3, kk = idx >> 11;
      int k = kk * 32 + (l >> 4) * 8 + j, n = nt * 16 + (l & 15);
      fWf[idx] = f2bf(fin_W1[k * HH + n]);
    }
  } else {
    const int layer = blk - 1;
    __shared__ float cat[96 * 64];
    const float* W1l = W1 + (size_t)layer * NDIM * HH;
    for (int idx = tid; idx < 4096; idx += 256) cat[idx] = W1l[idx];
    for (int idx = tid; idx < 2048; idx += 256) {
      int a = idx >> 6, n = idx & 63;
      float s = 0.f;
      for (int k = 0; k < 64; ++k) s += edge_W[a * HH + k] * W1l[(64 + k) * HH + n];
      cat[(64 + a) * 64 + n] = s;
    }
    if (tid < 64) {
      float s = b1[layer * HH + tid];
      for (int k = 0; k < 64; ++k) s += edge_b[k] * W1l[(64 + k) * HH + tid];
      b1p[layer * HH + tid] = s;
    }
    __syncthreads();
    for (int idx = tid; idx < 6144; idx += 256) {
      int j = idx & 7, l = (idx >> 3) & 63, nt = (idx >> 9) & 3, kk = idx >> 11;
      int k = kk * 32 + (l >> 4) * 8 + j, n = nt * 16 + (l & 15);
      W1f[layer * 6144 + idx] = f2bf(cat[k * 64 + n]);
    }
    for (int idx = tid; idx < 4096; idx += 256) {
      int j = idx & 7, l = (idx >> 3) & 63, nt = (idx >> 9) & 3, kk = idx >> 11;
      int k = kk * 32 + (l >> 4) * 8 + j, n = nt * 16 + (l & 15);
      W2f[layer * 4096 + idx] = f2bf(W2[((size_t)layer * HH + k) * HH + n]);
    }
  }
}

// ------------------------------------------------------- counting sort -----
__global__ __launch_bounds__(256)
void hist_kernel(const int* __restrict__ ei, int* __restrict__ cnt)
{
  int e = blockIdx.x * 256 + threadIdx.x;
  if (e < EE) atomicAdd(&cnt[ei[EE + e]], 1);
}

__global__ __launch_bounds__(256)
void chunk_sum(const int* __restrict__ cnt, int* __restrict__ bsum)
{
  int i = blockIdx.x * 256 + threadIdx.x;
  int v = (i < NN) ? cnt[i] : 0;
  int lane = threadIdx.x & 63, wv = threadIdx.x >> 6;
#pragma unroll
  for (int m = 1; m < 64; m <<= 1) v += __shfl_xor(v, m, 64);
  __shared__ int ws4[4];
  if (lane == 0) ws4[wv] = v;
  __syncthreads();
  if (threadIdx.x == 0) bsum[blockIdx.x] = ws4[0] + ws4[1] + ws4[2] + ws4[3];
}

__global__ __launch_bounds__(64)
void scan_small(int* __restrict__ bsum)
{
  int lane = threadIdx.x;
  int carry = 0;
  for (int r = 0; r < (NBLK + 63) / 64; ++r) {
    int idx = r * 64 + lane;
    int v = (idx < NBLK) ? bsum[idx] : 0;
    int s = v;
#pragma unroll
    for (int d = 1; d < 64; d <<= 1) {
      int t = __shfl_up(s, d, 64);
      if (lane >= d) s += t;
    }
    if (idx < NBLK) bsum[idx] = s - v + carry;
    carry += __shfl(s, 63, 64);
  }
}

__global__ __launch_bounds__(256)
void scan_write(int* __restrict__ cursor, const int* __restrict__ bsum)
{
  int i = blockIdx.x * 256 + threadIdx.x;
  int v = (i < NN) ? cursor[i] : 0;
  int lane = threadIdx.x & 63, wv = threadIdx.x >> 6;
  int s = v;
#pragma unroll
  for (int d = 1; d < 64; d <<= 1) {
    int t = __shfl_up(s, d, 64);
    if (lane >= d) s += t;
  }
  __shared__ int ws4[4];
  if (lane == 63) ws4[wv] = s;
  __syncthreads();
  int wo = 0;
  for (int w = 0; w < wv; ++w) wo += ws4[w];
  if (i < NN) cursor[i] = s - v + wo + bsum[blockIdx.x];
}

__global__ __launch_bounds__(256)
void scatter_kernel(const int* __restrict__ ei, const float* __restrict__ edge_attr,
                    int* __restrict__ cursor, int* __restrict__ srcp,
                    int* __restrict__ dstp, u16* __restrict__ eap)
{
  int e = blockIdx.x * 256 + threadIdx.x;
  if (e >= EE) return;
  int d = ei[EE + e];
  int pos = atomicAdd(&cursor[d], 1);
  srcp[pos] = ei[e];
  dstp[pos] = d;
  const f32x4* pa = reinterpret_cast<const f32x4*>(edge_attr + (size_t)e * EDIM);
  u16* po = eap + (size_t)pos * EDIM;
#pragma unroll
  for (int q = 0; q < 4; ++q) {
    f32x4 v0 = pa[q * 2], v1 = pa[q * 2 + 1];
    u16x8 o;
#pragma unroll
    for (int j = 0; j < 4; ++j) { o[j] = f2bf(v0[j]); o[4 + j] = f2bf(v1[j]); }
    *reinterpret_cast<u16x8*>(po + q * 8) = o;
  }
}

// ------------------------------------------------------------- node enc ----
#define LDX 136
__global__ __launch_bounds__(256, 2)
void node_enc(const float* __restrict__ x, const u16* __restrict__ nWf,
              const float* __restrict__ node_b, u16* __restrict__ h_bf)
{
  __shared__ u16 Xs[64 * LDX];
  const int tid = threadIdx.x;
  const int base = blockIdx.x * 64;
  const int lane = tid & 63, wv = tid >> 6;
  const int r16 = lane & 15, kg = lane >> 4;

  bf16x8 Bf[4][4];
#pragma unroll
  for (int kk = 0; kk < 4; ++kk)
#pragma unroll
    for (int nt = 0; nt < 4; ++nt)
      Bf[kk][nt] = *reinterpret_cast<const bf16x8*>(nWf + ((kk * 4 + nt) * 64 + lane) * 8);
  float bias[4];
#pragma unroll
  for (int nt = 0; nt < 4; ++nt) bias[nt] = node_b[nt * 16 + r16];

#pragma unroll
  for (int it = 0; it < 4; ++it) {
    int s = it * 256 + tid;
    int r = s >> 4, c = (s & 15) * 8;
    int node = base + r;
    u16x8 o;
    if (node < NN) {
      const f32x4* px = reinterpret_cast<const f32x4*>(x + (size_t)node * NDIM + c);
      f32x4 v0 = px[0], v1 = px[1];
#pragma unroll
      for (int j = 0; j < 4; ++j) { o[j] = f2bf(v0[j]); o[4 + j] = f2bf(v1[j]); }
    } else {
#pragma unroll
      for (int j = 0; j < 8; ++j) o[j] = 0;
    }
    *reinterpret_cast<u16x8*>(&Xs[r * LDX + c]) = o;
  }
  __syncthreads();

  f32x4 acc[4];
#pragma unroll
  for (int nt = 0; nt < 4; ++nt) acc[nt] = (f32x4){0.f, 0.f, 0.f, 0.f};
#pragma unroll
  for (int kk = 0; kk < 4; ++kk) {
    bf16x8 a = *reinterpret_cast<const bf16x8*>(&Xs[(wv * 16 + r16) * LDX + kk * 32 + kg * 8]);
#pragma unroll
    for (int nt = 0; nt < 4; ++nt)
      acc[nt] = __builtin_amdgcn_mfma_f32_16x16x32_bf16(a, Bf[kk][nt], acc[nt], 0, 0, 0);
  }
#pragma unroll
  for (int j = 0; j < 4; ++j) {
    int node = base + wv * 16 + kg * 4 + j;
    if (node < NN) {
#pragma unroll
      for (int nt = 0; nt < 4; ++nt)
        h_bf[(size_t)node * HH + nt * 16 + r16] = f2bf(acc[nt][j] + bias[nt]);
    }
  }
}

// ---------------------------------------------- message (dst-sorted) -------
#define LDI 104   // 96 + 8 pad (u16)
#define LDM 72    // 64 + 8 pad (u16)
#define SMS 66    // f32 stride of message tile
__global__ __launch_bounds__(256, 2)
void msg_sorted(const int* __restrict__ srcp, const int* __restrict__ dstp,
                const u16* __restrict__ eap, const u16* __restrict__ h_bf,
                float* __restrict__ h32, const u16* __restrict__ W1f,
                const u16* __restrict__ W2f, const float* __restrict__ b1p,
                const float* __restrict__ b2a, int layer)
{
  // In (u16, 64xLDI) and Sm (f32, 64xSMS) alias: In dead after GEMM1,
  // Sm written after the barrier that follows GEMM2.
  __shared__ __align__(16) char bufRaw[64 * SMS * 4];
  u16* In = reinterpret_cast<u16*>(bufRaw);
  float* Sm = reinterpret_cast<float*>(bufRaw);
  __shared__ u16 M1[4][16 * LDM];
  __shared__ int src_s[64], dst_s[64], segpos[64];
  __shared__ int segn;

  const int tid = threadIdx.x;
  const int base = blockIdx.x * 64;
  const int lane = tid & 63, wv = tid >> 6;
  const int r16 = lane & 15, kg = lane >> 4;

  if (tid < 64) src_s[tid] = srcp[base + tid];
  else if (tid < 128) dst_s[tid - 64] = dstp[base + tid - 64];

  bf16x8 B1[3][4], B2[2][4];
  const u16* w1 = W1f + layer * 6144;
  const u16* w2 = W2f + layer * 4096;
#pragma unroll
  for (int kk = 0; kk < 3; ++kk)
#pragma unroll
    for (int nt = 0; nt < 4; ++nt)
      B1[kk][nt] = *reinterpret_cast<const bf16x8*>(w1 + ((kk * 4 + nt) * 64 + lane) * 8);
#pragma unroll
  for (int kk = 0; kk < 2; ++kk)
#pragma unroll
    for (int nt = 0; nt < 4; ++nt)
      B2[kk][nt] = *reinterpret_cast<const bf16x8*>(w2 + ((kk * 4 + nt) * 64 + lane) * 8);
  float b1v[4], b2v[4];
#pragma unroll
  for (int nt = 0; nt < 4; ++nt) {
    b1v[nt] = b1p[layer * HH + nt * 16 + r16];
    b2v[nt] = b2a[layer * HH + nt * 16 + r16];
  }
  __syncthreads();  // indices ready

  // stage h_bf[src]+h_bf[dst] into In[:,0:64]  (dst rows are ~uniform -> L1)
#pragma unroll
  for (int it = 0; it < 2; ++it) {
    int s = it * 256 + tid;
    int e = s >> 3, c = (s & 7) * 8;
    u16x8 va = *reinterpret_cast<const u16x8*>(h_bf + (size_t)src_s[e] * HH + c);
    u16x8 vb = *reinterpret_cast<const u16x8*>(h_bf + (size_t)dst_s[e] * HH + c);
    u16x8 o;
#pragma unroll
    for (int j = 0; j < 8; ++j) o[j] = f2bf(bf2f(va[j]) + bf2f(vb[j]));
    *reinterpret_cast<u16x8*>(&In[e * LDI + c]) = o;
  }
  // stage pre-converted bf16 edge_attr into In[:,64:96]
  {
    int e = tid >> 2, c = (tid & 3) * 8;
    u16x8 v = *reinterpret_cast<const u16x8*>(eap + (size_t)(base + e) * EDIM + c);
    *reinterpret_cast<u16x8*>(&In[e * LDI + 64 + c]) = v;
  }
  // wave 0: segment boundaries of the sorted dst tile
  if (wv == 0) {
    bool st = (lane == 0) || (dst_s[lane] != dst_s[lane - 1]);
    unsigned long long m = __ballot(st);
    if (st) {
      int rk = __popcll(m & ((1ull << lane) - 1ull));
      segpos[rk] = lane;
    }
    if (lane == 0) segn = __popcll(m);
  }
  __syncthreads();

  // GEMM1: [64,96] @ [96,64]
  f32x4 acc[4];
#pragma unroll
  for (int nt = 0; nt < 4; ++nt) acc[nt] = (f32x4){0.f, 0.f, 0.f, 0.f};
#pragma unroll
  for (int kk = 0; kk < 3; ++kk) {
    bf16x8 a = *reinterpret_cast<const bf16x8*>(&In[(wv * 16 + r16) * LDI + kk * 32 + kg * 8]);
#pragma unroll
    for (int nt = 0; nt < 4; ++nt)
      acc[nt] = __builtin_amdgcn_mfma_f32_16x16x32_bf16(a, B1[kk][nt], acc[nt], 0, 0, 0);
  }
  // relu+bias -> per-wave M1 (C layout -> A layout); M1 is wave-private
#pragma unroll
  for (int nt = 0; nt < 4; ++nt)
#pragma unroll
    for (int j = 0; j < 4; ++j) {
      float v = fmaxf(acc[nt][j] + b1v[nt], 0.f);
      M1[wv][(kg * 4 + j) * LDM + nt * 16 + r16] = f2bf(v);
    }
  __syncthreads();   // all In reads done; also covers M1 visibility

  // GEMM2: [64,64] @ [64,64]
  f32x4 acc2[4];
#pragma unroll
  for (int nt = 0; nt < 4; ++nt) acc2[nt] = (f32x4){0.f, 0.f, 0.f, 0.f};
#pragma unroll
  for (int kk = 0; kk < 2; ++kk) {
    bf16x8 a = *reinterpret_cast<const bf16x8*>(&M1[wv][r16 * LDM + kk * 32 + kg * 8]);
#pragma unroll
    for (int nt = 0; nt < 4; ++nt)
      acc2[nt] = __builtin_amdgcn_mfma_f32_16x16x32_bf16(a, B2[kk][nt], acc2[nt], 0, 0, 0);
  }
  __syncthreads();   // In fully dead everywhere -> safe to write Sm (alias)

  // message tile (+b2 per edge) to LDS
#pragma unroll
  for (int nt = 0; nt < 4; ++nt)
#pragma unroll
    for (int j = 0; j < 4; ++j)
      Sm[(wv * 16 + kg * 4 + j) * SMS + nt * 16 + r16] = acc2[nt][j] + b2v[nt];
  __syncthreads();

  // segmented reduce: one coalesced 64-lane atomic row per segment
  int ns = segn;
  for (int s = wv; s < ns; s += 4) {
    int r0 = segpos[s];
    int r1 = (s + 1 < ns) ? segpos[s + 1] : 64;
    float sum = 0.f;
    for (int r = r0; r < r1; ++r) sum += Sm[r * SMS + lane];
    unsafeAtomicAdd(&h32[(size_t)dst_s[r0] * HH + lane], sum);
  }
}

// ------------------------------------------ message (fallback, atomic) -----
__global__ __launch_bounds__(256, 2)
void msg_kernel(const int* __restrict__ ei, const float* __restrict__ edge_attr,
                const u16* __restrict__ h_bf, float* __restrict__ h32,
                const u16* __restrict__ W1f, const u16* __restrict__ W2f,
                const float* __restrict__ b1p, const float* __restrict__ b2a,
                int layer)
{
  __shared__ u16 In[64 * LDI];
  __shared__ u16 M1[4][16 * LDM];
  __shared__ int src_s[64], dst_s[64];

  const int tid = threadIdx.x;
  const int base = blockIdx.x * 64;
  const int lane = tid & 63, wv = tid >> 6;
  const int r16 = lane & 15, kg = lane >> 4;

  if (tid < 64) src_s[tid] = ei[base + tid];
  else if (tid < 128) dst_s[tid - 64] = ei[EE + base + tid - 64];

  bf16x8 B1[3][4], B2[2][4];
  const u16* w1 = W1f + layer * 6144;
  const u16* w2 = W2f + layer * 4096;
#pragma unroll
  for (int kk = 0; kk < 3; ++kk)
#pragma unroll
    for (int nt = 0; nt < 4; ++nt)
      B1[kk][nt] = *reinterpret_cast<const bf16x8*>(w1 + ((kk * 4 + nt) * 64 + lane) * 8);
#pragma unroll
  for (int kk = 0; kk < 2; ++kk)
#pragma unroll
    for (int nt = 0; nt < 4; ++nt)
      B2[kk][nt] = *reinterpret_cast<const bf16x8*>(w2 + ((kk * 4 + nt) * 64 + lane) * 8);
  float b1v[4], b2v[4];
#pragma unroll
  for (int nt = 0; nt < 4; ++nt) {
    b1v[nt] = b1p[layer * HH + nt * 16 + r16];
    b2v[nt] = b2a[layer * HH + nt * 16 + r16];
  }
  __syncthreads();

#pragma unroll
  for (int it = 0; it < 2; ++it) {
    int s = it * 256 + tid;
    int e = s >> 3, c = (s & 7) * 8;
    u16x8 va = *reinterpret_cast<const u16x8*>(h_bf + (size_t)src_s[e] * HH + c);
    u16x8 vb = *reinterpret_cast<const u16x8*>(h_bf + (size_t)dst_s[e] * HH + c);
    u16x8 o;
#pragma unroll
    for (int j = 0; j < 8; ++j) o[j] = f2bf(bf2f(va[j]) + bf2f(vb[j]));
    *reinterpret_cast<u16x8*>(&In[e * LDI + c]) = o;
  }
  {
    int e = tid >> 2, c = (tid & 3) * 8;
    const f32x4* pa = reinterpret_cast<const f32x4*>(edge_attr + (size_t)(base + e) * EDIM + c);
    f32x4 v0 = pa[0], v1 = pa[1];
    u16x8 o;
#pragma unroll
    for (int j = 0; j < 4; ++j) { o[j] = f2bf(v0[j]); o[4 + j] = f2bf(v1[j]); }
    *reinterpret_cast<u16x8*>(&In[e * LDI + 64 + c]) = o;
  }
  __syncthreads();

  f32x4 acc[4];
#pragma unroll
  for (int nt = 0; nt < 4; ++nt) acc[nt] = (f32x4){0.f, 0.f, 0.f, 0.f};
#pragma unroll
  for (int kk = 0; kk < 3; ++kk) {
    bf16x8 a = *reinterpret_cast<const bf16x8*>(&In[(wv * 16 + r16) * LDI + kk * 32 + kg * 8]);
#pragma unroll
    for (int nt = 0; nt < 4; ++nt)
      acc[nt] = __builtin_amdgcn_mfma_f32_16x16x32_bf16(a, B1[kk][nt], acc[nt], 0, 0, 0);
  }
#pragma unroll
  for (int nt = 0; nt < 4; ++nt)
#pragma unroll
    for (int j = 0; j < 4; ++j) {
      float v = fmaxf(acc[nt][j] + b1v[nt], 0.f);
      M1[wv][(kg * 4 + j) * LDM + nt * 16 + r16] = f2bf(v);
    }
  __syncthreads();

  f32x4 acc2[4];
#pragma unroll
  for (int nt = 0; nt < 4; ++nt) acc2[nt] = (f32x4){0.f, 0.f, 0.f, 0.f};
#pragma unroll
  for (int kk = 0; kk < 2; ++kk) {
    bf16x8 a = *reinterpret_cast<const bf16x8*>(&M1[wv][r16 * LDM + kk * 32 + kg * 8]);
#pragma unroll
    for (int nt = 0; nt < 4; ++nt)
      acc2[nt] = __builtin_amdgcn_mfma_f32_16x16x32_bf16(a, B2[kk][nt], acc2[nt], 0, 0, 0);
  }
  int dn[4];
#pragma unroll
  for (int j = 0; j < 4; ++j) dn[j] = dst_s[wv * 16 + kg * 4 + j];
#pragma unroll
  for (int j = 0; j < 4; ++j)
#pragma unroll
    for (int nt = 0; nt < 4; ++nt)
      unsafeAtomicAdd(&h32[(size_t)dn[j] * HH + nt * 16 + r16], acc2[nt][j] + b2v[nt]);
}

// ------------------------------------------------------------- h32->bf16 ---
__global__ __launch_bounds__(256)
void cvt_h(const float* __restrict__ h32, u16* __restrict__ h_bf)
{
  size_t i = ((size_t)blockIdx.x * 256 + threadIdx.x) * 8;
  if (i >= (size_t)NN * HH) return;
  const f32x4* p = reinterpret_cast<const f32x4*>(h32 + i);
  f32x4 v0 = p[0], v1 = p[1];
  u16x8 o;
#pragma unroll
  for (int j = 0; j < 4; ++j) { o[j] = f2bf(v0[j]); o[4 + j] = f2bf(v1[j]); }
  *reinterpret_cast<u16x8*>(h_bf + i) = o;
}

// ---------------------------------------------------------------- final ----
#define LDF 136
__global__ __launch_bounds__(256, 2)
void final_kernel(const int* __restrict__ ei, const u16* __restrict__ h_bf,
                  const u16* __restrict__ fWf, const float* __restrict__ fin_b1,
                  const float* __restrict__ fin_W2, const float* __restrict__ fin_b2,
                  float* __restrict__ out)
{
  __shared__ u16 In[64 * LDF];
  __shared__ int src_s[64], dst_s[64];
  const int tid = threadIdx.x;
  const int base = blockIdx.x * 64;
  const int lane = tid & 63, wv = tid >> 6;
  const int r16 = lane & 15, kg = lane >> 4;

  if (tid < 64) src_s[tid] = ei[base + tid];
  else if (tid < 128) dst_s[tid - 64] = ei[EE + base + tid - 64];

  bf16x8 Bf[4][4];
#pragma unroll
  for (int kk = 0; kk < 4; ++kk)
#pragma unroll
    for (int nt = 0; nt < 4; ++nt)
      Bf[kk][nt] = *reinterpret_cast<const bf16x8*>(fWf + ((kk * 4 + nt) * 64 + lane) * 8);
  float b1v[4], w2v[4];
#pragma unroll
  for (int nt = 0; nt < 4; ++nt) {
    b1v[nt] = fin_b1[nt * 16 + r16];
    w2v[nt] = fin_W2[nt * 16 + r16];
  }
  const float bb = fin_b2[0];
  __syncthreads();

#pragma unroll
  for (int it = 0; it < 4; ++it) {
    int s = it * 256 + tid;
    int e = s >> 4, g = s & 15, c = (g & 7) * 8;
    int nd = (g < 8) ? src_s[e] : dst_s[e];
    u16x8 v = *reinterpret_cast<const u16x8*>(h_bf + (size_t)nd * HH + c);
    *reinterpret_cast<u16x8*>(&In[e * LDF + g * 8]) = v;
  }
  __syncthreads();

  f32x4 acc[4];
#pragma unroll
  for (int nt = 0; nt < 4; ++nt) acc[nt] = (f32x4){0.f, 0.f, 0.f, 0.f};
#pragma unroll
  for (int kk = 0; kk < 4; ++kk) {
    bf16x8 a = *reinterpret_cast<const bf16x8*>(&In[(wv * 16 + r16) * LDF + kk * 32 + kg * 8]);
#pragma unroll
    for (int nt = 0; nt < 4; ++nt)
      acc[nt] = __builtin_amdgcn_mfma_f32_16x16x32_bf16(a, Bf[kk][nt], acc[nt], 0, 0, 0);
  }
  float p[4];
#pragma unroll
  for (int j = 0; j < 4; ++j) {
    float s = 0.f;
#pragma unroll
    for (int nt = 0; nt < 4; ++nt) s += fmaxf(acc[nt][j] + b1v[nt], 0.f) * w2v[nt];
    p[j] = s;
  }
#pragma unroll
  for (int j = 0; j < 4; ++j)
#pragma unroll
    for (int m = 1; m < 16; m <<= 1)
      p[j] += __shfl_xor(p[j], m, 64);
  if (r16 == 0) {
#pragma unroll
    for (int j = 0; j < 4; ++j)
      out[base + wv * 16 + kg * 4 + j] = p[j] + bb;
  }
}

// ---------------------------------------------------------------- launch ---
extern "C" void kernel_launch(void* const* d_in, const int* in_sizes, int n_in,
                              void* d_out, int out_size, void* d_ws, size_t ws_size,
                              hipStream_t stream)
{
  const float* x      = (const float*)d_in[0];
  const float* eattr  = (const float*)d_in[1];
  const int*   ei     = (const int*)d_in[2];
  const float* node_W = (const float*)d_in[3];
  const float* node_b = (const float*)d_in[4];
  const float* edge_W = (const float*)d_in[5];
  const float* edge_b = (const float*)d_in[6];
  const float* W1     = (const float*)d_in[7];
  const float* b1     = (const float*)d_in[8];
  const float* W2     = (const float*)d_in[9];
  const float* b2     = (const float*)d_in[10];
  const float* fin_W1 = (const float*)d_in[11];
  const float* fin_b1 = (const float*)d_in[12];
  const float* fin_W2 = (const float*)d_in[13];
  const float* fin_b2 = (const float*)d_in[14];

  char* ws   = (char*)d_ws;
  float* h32 = (float*)(ws + OFF_H32);
  u16* h_bf  = (u16*)(ws + OFF_HBF);
  u16* nWf   = (u16*)(ws + OFF_NWF);
  u16* W1f   = (u16*)(ws + OFF_W1F);
  u16* W2f   = (u16*)(ws + OFF_W2F);
  u16* fWf   = (u16*)(ws + OFF_FWF);
  float* b1p = (float*)(ws + OFF_B1P);

  setup_kernel<<<6, 256, 0, stream>>>(node_W, edge_W, edge_b, W1, b1, W2, fin_W1,
                                      nWf, W1f, W2f, fWf, b1p);
  node_enc<<<(NN + 63) / 64, 256, 0, stream>>>(x, nWf, node_b, h_bf);

  if (ws_size >= WS_NEED) {
    int* cursor = (int*)(ws + OFF_CUR);
    int* bsum   = (int*)(ws + OFF_BSUM);
    int* srcp   = (int*)(ws + OFF_SRCP);
    int* dstp   = (int*)(ws + OFF_DSTP);
    u16* eap    = (u16*)(ws + OFF_EAP);

    hipMemsetAsync(cursor, 0, 50176 * sizeof(int), stream);
    hist_kernel<<<(EE + 255) / 256, 256, 0, stream>>>(ei, cursor);
    chunk_sum<<<NBLK, 256, 0, stream>>>(cursor, bsum);
    scan_small<<<1, 64, 0, stream>>>(bsum);
    scan_write<<<NBLK, 256, 0, stream>>>(cursor, bsum);
    scatter_kernel<<<(EE + 255) / 256, 256, 0, stream>>>(ei, eattr, cursor, srcp, dstp, eap);

    for (int l = 0; l < 4; ++l) {
      hipMemsetAsync(h32, 0, (size_t)NN * HH * sizeof(float), stream);
      msg_sorted<<<EE / 64, 256, 0, stream>>>(srcp, dstp, eap, h_bf, h32, W1f, W2f, b1p, b2, l);
      cvt_h<<<((size_t)NN * HH / 8 + 255) / 256, 256, 0, stream>>>(h32, h_bf);
    }
  } else {
    for (int l = 0; l < 4; ++l) {
      hipMemsetAsync(h32, 0, (size_t)NN * HH * sizeof(float), stream);
      msg_kernel<<<EE / 64, 256, 0, stream>>>(ei, eattr, h_bf, h32, W1f, W2f, b1p, b2, l);
      cvt_h<<<((size_t)NN * HH / 8 + 255) / 256, 256, 0, stream>>>(h32, h_bf);
    }
  }
  final_kernel<<<EE / 64, 256, 0, stream>>>(ei, h_bf, fWf, fin_b1, fin_W2, fin_b2,
                                            (float*)d_out);
}